// Round 20
// baseline (1833.277 us; speedup 1.0000x reference)
//
#include <hip/hip_runtime.h>
#include <hip/hip_bf16.h>
#include <math.h>

#define D_MODEL 2048
#define EDIM    4096
#define NSTATE  16
#define LSEQ    256
#define BATCH   4
#define NLAYER  6
#define FDIM    80
#define TCH     32     // scan t-chunk length
#define NCH     8      // number of t-chunks

typedef __attribute__((ext_vector_type(8))) short bf16x8;
typedef __attribute__((ext_vector_type(4))) float f32x4;

__device__ __forceinline__ float silu_f(float x) { return x / (1.f + __expf(-x)); }

__device__ __forceinline__ float softplus_f(float v) {
  return (v > 20.f) ? v : __logf(1.f + __expf(v));
}

// RNE float -> bf16 bits
__device__ __forceinline__ unsigned short f2bf(float f) {
  unsigned u = __float_as_uint(f);
  unsigned r = u + 0x7fffu + ((u >> 16) & 1u);
  return (unsigned short)(r >> 16);
}

__device__ __forceinline__ float bf2f(unsigned short u) {
  return __uint_as_float((unsigned)u << 16);
}

__device__ __forceinline__ void gload_lds16(const void* g, void* l) {
  __builtin_amdgcn_global_load_lds(
      (const __attribute__((address_space(1))) unsigned int*)g,
      (__attribute__((address_space(3))) unsigned int*)l, 16, 0, 0);
}

// ---------------- embedding ----------------
__global__ __launch_bounds__(256) void embed_kernel(
    const float* __restrict__ x, const float* __restrict__ W,
    const float* __restrict__ bias, float* __restrict__ h)
{
  int col = blockIdx.x * 256 + threadIdx.x;
  int row = blockIdx.y;
  int b = row >> 8, l = row & 255;
  const float* xp = x + (size_t)b * FDIM * LSEQ + l;
  float acc = bias[col];
  #pragma unroll 8
  for (int f = 0; f < FDIM; ++f)
    acc = fmaf(xp[(size_t)f * LSEQ], W[(size_t)f * D_MODEL + col], acc);
  h[(size_t)row * D_MODEL + col] = acc;
}

// ---------------- rmsnorm ----------------
__global__ __launch_bounds__(256) void rmsnorm_kernel(
    const float* __restrict__ h, const float* __restrict__ w, unsigned short* __restrict__ u)
{
  int row = blockIdx.x;
  const float* hr = h + (size_t)row * D_MODEL;
  float s = 0.f;
  for (int i = threadIdx.x; i < D_MODEL; i += 256) { float v = hr[i]; s = fmaf(v, v, s); }
  #pragma unroll
  for (int o = 32; o > 0; o >>= 1) s += __shfl_down(s, o);
  __shared__ float red[4];
  int lane = threadIdx.x & 63, wid = threadIdx.x >> 6;
  if (lane == 0) red[wid] = s;
  __syncthreads();
  float total = red[0] + red[1] + red[2] + red[3];
  float scale = rsqrtf(total * (1.f / D_MODEL) + 1e-5f);
  unsigned short* ur = u + (size_t)row * D_MODEL;
  for (int i = threadIdx.x; i < D_MODEL; i += 256) ur[i] = f2bf(hr[i] * scale * w[i]);
}

// ---------------- weight transpose+convert: W[K][N] f32 -> WT[N][K] bf16 ----------------
__global__ __launch_bounds__(256) void wtrans_kernel(
    const float* __restrict__ W, unsigned short* __restrict__ WT, int K, int N)
{
  __shared__ float t[64][65];
  const int k0 = blockIdx.y * 64, n0 = blockIdx.x * 64;
  const int tc = (threadIdx.x & 15) << 2;
  const int tr = threadIdx.x >> 4;
  #pragma unroll
  for (int i = 0; i < 4; ++i) {
    int r = tr + (i << 4);
    float4 v = *(const float4*)(W + (size_t)(k0 + r) * N + n0 + tc);
    t[r][tc + 0] = v.x; t[r][tc + 1] = v.y; t[r][tc + 2] = v.z; t[r][tc + 3] = v.w;
  }
  __syncthreads();
  #pragma unroll
  for (int i = 0; i < 4; ++i) {
    int rr = tr + (i << 4);
    ushort4 o;
    o.x = f2bf(t[tc + 0][rr]);
    o.y = f2bf(t[tc + 1][rr]);
    o.z = f2bf(t[tc + 2][rr]);
    o.w = f2bf(t[tc + 3][rr]);
    *(ushort4*)(WT + (size_t)(n0 + rr) * K + k0 + tc) = o;
  }
}

// ---------------- W_x transpose (all layers, once): Wx[l][e][j] -> WxT[l][j][e] ------
__global__ __launch_bounds__(256) void wxt_kernel(
    const float* __restrict__ Wx, float* __restrict__ WxT)
{
  const int e = blockIdx.x * 256 + threadIdx.x;
  const int j = blockIdx.y;
  const int l = blockIdx.z;
  WxT[((size_t)l * 34 + j) * EDIM + e] = Wx[(size_t)l * EDIM * 34 + (size_t)e * 34 + j];
}

// ---------------- bf16 MFMA GEMM (R4 structure) ----------------
template<int BN>
__global__ __launch_bounds__(256) void gemm_bf16(
    const unsigned short* __restrict__ A, int lda,
    const unsigned short* __restrict__ BT, int ldb,
    const float* bias,
    const float* resid, int ldr,
    float* __restrict__ C, int ldc, int K)
{
  constexpr int BM = 128;
  constexpr int FN = BN / 32;
  __shared__ unsigned short As[2][BM * 32];
  __shared__ unsigned short Bs[2][BN * 32];
  const int tid  = threadIdx.x;
  const int wave = tid >> 6;
  const int lane = tid & 63;

  const int nwg = gridDim.x * gridDim.y;
  const int cpx = nwg >> 3;
  int flat = blockIdx.y * gridDim.x + blockIdx.x;
  flat = (flat & 7) * cpx + (flat >> 3);
  const int bm = (flat / gridDim.x) * BM;
  const int bn = (flat % gridDim.x) * BN;

  const int wr = (wave >> 1) * 64;
  const int wc = (wave & 1) * (BN / 2);
  const int srow = lane >> 2;
  const int scol = (lane & 3) * 8;

  auto stage = [&](int buf, int k0) {
    #pragma unroll
    for (int i = 0; i < BM / 64; ++i) {
      int c = wave + i * 4;
      gload_lds16(A + (size_t)(bm + c * 16 + srow) * lda + k0 + scol, &As[buf][c * 512]);
    }
    #pragma unroll
    for (int i = 0; i < BN / 64; ++i) {
      int c = wave + i * 4;
      gload_lds16(BT + (size_t)(bn + c * 16 + srow) * ldb + k0 + scol, &Bs[buf][c * 512]);
    }
  };

  f32x4 acc[4][FN];
  #pragma unroll
  for (int m = 0; m < 4; ++m)
    #pragma unroll
    for (int n = 0; n < FN; ++n)
      acc[m][n] = (f32x4){0.f, 0.f, 0.f, 0.f};

  stage(0, 0);
  const int nk = K >> 5;
  for (int t = 0; t < nk; ++t) {
    const int cur = t & 1;
    __syncthreads();
    if (t + 1 < nk) stage(cur ^ 1, (t + 1) << 5);
    bf16x8 af[4], bfr[FN];
    #pragma unroll
    for (int m = 0; m < 4; ++m)
      af[m] = *(const bf16x8*)&As[cur][(wr + m * 16 + (lane & 15)) * 32 + (lane >> 4) * 8];
    #pragma unroll
    for (int n = 0; n < FN; ++n)
      bfr[n] = *(const bf16x8*)&Bs[cur][(wc + n * 16 + (lane & 15)) * 32 + (lane >> 4) * 8];
    #pragma unroll
    for (int m = 0; m < 4; ++m)
      #pragma unroll
      for (int n = 0; n < FN; ++n)
        acc[m][n] = __builtin_amdgcn_mfma_f32_16x16x32_bf16(af[m], bfr[n], acc[m][n], 0, 0, 0);
  }

  const int rbase = (lane >> 4) * 4;
  const int cbase = lane & 15;
  #pragma unroll
  for (int m = 0; m < 4; ++m) {
    #pragma unroll
    for (int n = 0; n < FN; ++n) {
      const int col = bn + wc + n * 16 + cbase;
      const float bv = bias ? bias[col] : 0.f;
      #pragma unroll
      for (int r = 0; r < 4; ++r) {
        const int row = bm + wr + m * 16 + rbase + r;
        float v = acc[m][n][r] + bv;
        if (resid) v += resid[(size_t)row * ldr + col];
        C[(size_t)row * ldc + col] = v;
      }
    }
  }
}

// ---------------- fused conv+silu+dbc (R9 structure; xab output in bf16) ----------------
__global__ __launch_bounds__(256) void conv_dbc_kernel(
    const float* __restrict__ xz, const float* __restrict__ cw,
    const float* __restrict__ cb, const float* __restrict__ WxT,
    unsigned short* __restrict__ xab, float* __restrict__ dbc)
{
  const int row = blockIdx.x;
  const int l = row & (LSEQ - 1);
  const int tid = threadIdx.x;
  float a[16];
  const float* base_row = xz + (size_t)row * 8192;
  #pragma unroll
  for (int k = 0; k < 16; ++k) {
    const int e = k * 256 + tid;
    float4 w = *(const float4*)(cw + (size_t)e * 4);
    const float* base = base_row + e;
    float v = cb[e];
    v = fmaf(w.w, base[0], v);
    if (l >= 1) v = fmaf(w.z, base[-8192], v);
    if (l >= 2) v = fmaf(w.y, base[-2 * 8192], v);
    if (l >= 3) v = fmaf(w.x, base[-3 * 8192], v);
    v = silu_f(v);
    a[k] = v;
    xab[(size_t)row * EDIM + e] = f2bf(v);
  }
  __shared__ float red[34][4];
  const int lane = tid & 63, wid = tid >> 6;
  #pragma unroll
  for (int j = 0; j < 34; ++j) {
    const float* wr = WxT + (size_t)j * EDIM + tid;
    float s = 0.f;
    #pragma unroll
    for (int k = 0; k < 16; ++k)
      s = fmaf(a[k], wr[k * 256], s);
    #pragma unroll
    for (int o = 32; o > 0; o >>= 1) s += __shfl_down(s, o);
    if (lane == 0) red[j][wid] = s;
  }
  __syncthreads();
  if (tid < 34)
    dbc[(size_t)row * 34 + tid] = red[tid][0] + red[tid][1] + red[tid][2] + red[tid][3];
}

// ================= chunked selective scan (3 passes) =================
// h_t = a_t h + b_t is affine with diagonal a => exact 8-way t-chunk split.
// pass1: per chunk, local h from 0 + S = sum(dta)  (a_chunk = exp(Aa*S))
// pass2: compose exclusive prefixes per (b,e,n)
// pass3: re-run chunk seeded with prefix, emit y.
// Lane partition (R9/R14): lane = ch(0..7) + 8*g(0..7), 2 states/lane, 32 ch/block.

__global__ __launch_bounds__(256) void scan_part_kernel(
    const unsigned short* __restrict__ xab, const float* __restrict__ dbc,
    const float* __restrict__ Wdt, const float* __restrict__ bdt,
    const float* __restrict__ Alog,
    float* __restrict__ hpart, float* __restrict__ Spart)
{
  __shared__ unsigned short sx[TCH * 32];   // 2 KB
  __shared__ float          sd01[TCH * 2];  // 256 B
  __shared__ unsigned short sBC[TCH * 32];  // 2 KB

  const int tid = threadIdx.x;
  const int b = blockIdx.x >> 7;
  const int chunk = blockIdx.x & 127;
  const int tc = blockIdx.y;
  const int wave = tid >> 6;
  const int lane = tid & 63;
  const int ch = lane & 7;
  const int g = lane >> 3;
  const int we = wave * 8 + ch;
  const int e = chunk * 32 + we;
  const int row0 = (b << 8) + tc * TCH;

  // stage
  const unsigned short* xsrc = xab + (size_t)row0 * EDIM + chunk * 32;
  const float* dsrc = dbc + (size_t)(b << 8) * 34;
  {
    int t = tid >> 3, q = tid & 7;   // 32 t x 8 quads = 256
    *(ushort4*)&sx[t * 32 + q * 4] = *(const ushort4*)&xsrc[(size_t)t * EDIM + q * 4];
  }
  if (tid < TCH) {
    float2 v = *(const float2*)&dsrc[(size_t)(tc * TCH + tid) * 34];
    *(float2*)&sd01[tid * 2] = v;
  }
  #pragma unroll
  for (int i = 0; i < 2; ++i) {
    int idx = i * 256 + tid;          // 32 t x 16 pairs = 512
    int t = idx >> 4, q = idx & 15;
    float2 v = *(const float2*)&dsrc[(size_t)(tc * TCH + t) * 34 + 2 + q * 2];
    ushort2 o; o.x = f2bf(v.x); o.y = f2bf(v.y);
    *(ushort2*)&sBC[t * 32 + q * 2] = o;
  }
  __syncthreads();

  const float w0 = Wdt[e], w1 = Wdt[EDIM + e], bde = bdt[e];
  const float Aa0 = -__expf(Alog[(size_t)e * 16 + g * 2]);
  const float Aa1 = -__expf(Alog[(size_t)e * 16 + g * 2 + 1]);
  float h0 = 0.f, h1 = 0.f, S = 0.f;

  #pragma unroll 4
  for (int t = 0; t < TCH; ++t) {
    float d0 = sd01[t * 2], d1 = sd01[t * 2 + 1];
    float v = fmaf(d1, w1, fmaf(d0, w0, bde));
    float dta = softplus_f(v);
    S += dta;
    float xv = bf2f(sx[t * 32 + we]);
    float dtxa = dta * xv;
    h0 = fmaf(__expf(dta * Aa0), h0, dtxa * bf2f(sBC[t * 32 + 2 * g]));
    h1 = fmaf(__expf(dta * Aa1), h1, dtxa * bf2f(sBC[t * 32 + 2 * g + 1]));
  }

  const size_t base = ((size_t)(b * NCH + tc) * EDIM + e);
  hpart[base * 16 + g * 2]     = h0;
  hpart[base * 16 + g * 2 + 1] = h1;
  if (g == 0) Spart[base] = S;
}

__global__ __launch_bounds__(256) void scan_prefix_kernel(
    const float* __restrict__ hpart, const float* __restrict__ Spart,
    const float* __restrict__ Alog, float* __restrict__ seed)
{
  const int id = blockIdx.x * 256 + threadIdx.x;   // over 4*4096*16
  const int n = id & 15;
  const int e = (id >> 4) & 4095;
  const int b = id >> 16;
  const float Aa = -__expf(Alog[(size_t)e * 16 + n]);
  float H = 0.f;
  #pragma unroll
  for (int c = 0; c < NCH; ++c) {
    const size_t base = ((size_t)(b * NCH + c) * EDIM + e);
    seed[base * 16 + n] = H;
    float a = __expf(Aa * Spart[base]);
    H = fmaf(a, H, hpart[base * 16 + n]);
  }
}

__global__ __launch_bounds__(256) void scan_final_kernel(
    const unsigned short* __restrict__ xab, const float* __restrict__ xz,
    const float* __restrict__ dbc, const float* __restrict__ seed,
    const float* __restrict__ Wdt, const float* __restrict__ bdt,
    const float* __restrict__ Alog, const float* __restrict__ Dpp,
    unsigned short* __restrict__ ybf)
{
  __shared__ unsigned short sx[TCH * 32];
  __shared__ unsigned short sz[TCH * 32];
  __shared__ float          sd01[TCH * 2];
  __shared__ unsigned short sBC[TCH * 32];

  const int tid = threadIdx.x;
  const int b = blockIdx.x >> 7;
  const int chunk = blockIdx.x & 127;
  const int tc = blockIdx.y;
  const int wave = tid >> 6;
  const int lane = tid & 63;
  const int ch = lane & 7;
  const int g = lane >> 3;
  const int we = wave * 8 + ch;
  const int e = chunk * 32 + we;
  const int row0 = (b << 8) + tc * TCH;

  const unsigned short* xsrc = xab + (size_t)row0 * EDIM + chunk * 32;
  const float* zsrc = xz + (size_t)row0 * 8192 + EDIM + chunk * 32;
  const float* dsrc = dbc + (size_t)(b << 8) * 34;
  {
    int t = tid >> 3, q = tid & 7;
    *(ushort4*)&sx[t * 32 + q * 4] = *(const ushort4*)&xsrc[(size_t)t * EDIM + q * 4];
    float4 v = *(const float4*)&zsrc[(size_t)t * 8192 + q * 4];
    ushort4 o; o.x = f2bf(v.x); o.y = f2bf(v.y); o.z = f2bf(v.z); o.w = f2bf(v.w);
    *(ushort4*)&sz[t * 32 + q * 4] = o;
  }
  if (tid < TCH) {
    float2 v = *(const float2*)&dsrc[(size_t)(tc * TCH + tid) * 34];
    *(float2*)&sd01[tid * 2] = v;
  }
  #pragma unroll
  for (int i = 0; i < 2; ++i) {
    int idx = i * 256 + tid;
    int t = idx >> 4, q = idx & 15;
    float2 v = *(const float2*)&dsrc[(size_t)(tc * TCH + t) * 34 + 2 + q * 2];
    ushort2 o; o.x = f2bf(v.x); o.y = f2bf(v.y);
    *(ushort2*)&sBC[t * 32 + q * 2] = o;
  }
  __syncthreads();

  const float w0 = Wdt[e], w1 = Wdt[EDIM + e], bde = bdt[e];
  const float Aa0 = -__expf(Alog[(size_t)e * 16 + g * 2]);
  const float Aa1 = -__expf(Alog[(size_t)e * 16 + g * 2 + 1]);
  const float dpe = Dpp[e];
  const size_t sbase = ((size_t)(b * NCH + tc) * EDIM + e) * 16;
  float h0 = seed[sbase + g * 2];
  float h1 = seed[sbase + g * 2 + 1];
  unsigned short* yp = ybf + (size_t)row0 * EDIM + e;

  #pragma unroll 4
  for (int t = 0; t < TCH; ++t) {
    float d0 = sd01[t * 2], d1 = sd01[t * 2 + 1];
    float v = fmaf(d1, w1, fmaf(d0, w0, bde));
    float dta = softplus_f(v);
    float xv = bf2f(sx[t * 32 + we]);
    float dtxa = dta * xv;
    h0 = fmaf(__expf(dta * Aa0), h0, dtxa * bf2f(sBC[t * 32 + 2 * g]));
    h1 = fmaf(__expf(dta * Aa1), h1, dtxa * bf2f(sBC[t * 32 + 2 * g + 1]));
    float part = fmaf(h0, bf2f(sBC[t * 32 + 16 + 2 * g]),
                      h1 * bf2f(sBC[t * 32 + 16 + 2 * g + 1]));
    part += __shfl_xor(part, 8);
    part += __shfl_xor(part, 16);
    part += __shfl_xor(part, 32);
    if (g == 0) {
      float yv = fmaf(dpe, xv, part);
      yp[(size_t)t * EDIM] = f2bf(yv * silu_f(bf2f(sz[t * 32 + we])));
    }
  }
}

// ---------------- split-K head GEMMs ----------------
template<int KS>
__global__ __launch_bounds__(256) void head_gemm_part(
    const float* __restrict__ in, int in_stride,
    const float* __restrict__ W, int N,
    float* __restrict__ part)
{
  const int j = blockIdx.x * 256 + threadIdx.x;
  const int b = blockIdx.y;
  const int s = blockIdx.z;
  const int k0 = s * KS;
  __shared__ float sIn[KS];
  if (threadIdx.x < KS) sIn[threadIdx.x] = in[(size_t)b * in_stride + k0 + threadIdx.x];
  __syncthreads();
  float acc = 0.f;
  #pragma unroll 8
  for (int k = 0; k < KS; ++k)
    acc = fmaf(sIn[k], W[(size_t)(k0 + k) * N + j], acc);
  part[((size_t)s * gridDim.y + b) * N + j] = acc;
}

__global__ __launch_bounds__(256) void head_reduce(
    const float* __restrict__ part, const float* __restrict__ bias,
    float* __restrict__ outp, int N, int S, int act)
{
  const int j = blockIdx.x * 256 + threadIdx.x;
  const int b = blockIdx.y;
  const int B = gridDim.y;
  float acc = bias[j];
  for (int s = 0; s < S; ++s)
    acc += part[((size_t)s * B + b) * N + j];
  if (act == 1) acc = silu_f(acc);
  else if (act == 2) acc = (acc > 0.f) ? acc : 0.01f * acc;
  outp[(size_t)b * N + j] = acc;
}

__global__ __launch_bounds__(256) void head_final_kernel(
    const float* __restrict__ g2, const float* __restrict__ W,
    const float* __restrict__ bb, float* __restrict__ out)
{
  int b_idx = threadIdx.x >> 6;
  int lane = threadIdx.x & 63;
  float s = 0.f;
  #pragma unroll
  for (int i = 0; i < 4; ++i) {
    int k = lane + i * 64;
    s = fmaf(g2[b_idx * 256 + k], W[k], s);
  }
  #pragma unroll
  for (int o = 32; o > 0; o >>= 1) s += __shfl_down(s, o);
  if (lane == 0) out[b_idx] = 1.f / (1.f + __expf(-(s + bb[0])));
}

extern "C" void kernel_launch(void* const* d_in, const int* in_sizes, int n_in,
                              void* d_out, int out_size, void* d_ws, size_t ws_size,
                              hipStream_t stream)
{
  const float* x      = (const float*)d_in[0];
  const float* W_emb  = (const float*)d_in[1];
  const float* b_emb  = (const float*)d_in[2];
  const float* norm_w = (const float*)d_in[3];
  const float* W_in   = (const float*)d_in[4];
  const float* b_in   = (const float*)d_in[5];
  const float* conv_w = (const float*)d_in[6];
  const float* conv_b = (const float*)d_in[7];
  const float* W_x    = (const float*)d_in[8];
  const float* W_dt   = (const float*)d_in[9];
  const float* b_dt   = (const float*)d_in[10];
  const float* A_log  = (const float*)d_in[11];
  const float* Dp     = (const float*)d_in[12];
  const float* W_out  = (const float*)d_in[13];
  const float* b_out  = (const float*)d_in[14];
  const float* W_f    = (const float*)d_in[15];
  const float* b_f    = (const float*)d_in[16];
  const float* W_h1   = (const float*)d_in[17];
  const float* b_h1   = (const float*)d_in[18];
  const float* W_h2   = (const float*)d_in[19];
  const float* b_h2   = (const float*)d_in[20];
  const float* W_h3   = (const float*)d_in[21];
  const float* b_h3   = (const float*)d_in[22];
  float* out = (float*)d_out;

  // workspace layout
  char* ws = (char*)d_ws;
  float*          hA   = (float*)ws;                ws += (size_t)1024 * 2048 * 4;
  float*          hB   = (float*)ws;                ws += (size_t)1024 * 2048 * 4;
  unsigned short* ubf  = (unsigned short*)ws;       ws += (size_t)1024 * 2048 * 2;
  float*          xz   = (float*)ws;                ws += (size_t)1024 * 8192 * 4;
  unsigned short* xab  = (unsigned short*)ws;       ws += (size_t)1024 * 4096 * 2;
  float*          dbc  = (float*)ws;                ws += (size_t)1024 * 40 * 4;
  unsigned short* ybf  = (unsigned short*)ws;       ws += (size_t)1024 * 4096 * 2;
  unsigned short* WT   = (unsigned short*)ws;       ws += (size_t)8192 * 2048 * 2;
  float*          WxT  = (float*)ws;                ws += (size_t)NLAYER * 34 * EDIM * 4;
  float*          hpart= (float*)ws;                ws += (size_t)BATCH * NCH * EDIM * 16 * 4; // 8 MB
  float*          Spart= (float*)ws;                ws += (size_t)BATCH * NCH * EDIM * 4;      // 0.5 MB
  float*          seed = (float*)ws;                ws += (size_t)BATCH * NCH * EDIM * 16 * 4; // 8 MB
  float*          part = (float*)ws;                ws += (size_t)16 * 4 * 1024 * 4;
  float*          fb   = (float*)ws;                ws += 4096 * 4;
  float*          g1b  = (float*)ws;                ws += 2048 * 4;
  float*          g2b  = (float*)ws;                ws += 1024 * 4;

  embed_kernel<<<dim3(D_MODEL / 256, 1024), 256, 0, stream>>>(x, W_emb, b_emb, hA);
  wxt_kernel<<<dim3(EDIM / 256, 34, NLAYER), 256, 0, stream>>>(W_x, WxT);

  float* hin = hA;
  float* hout = hB;
  for (int i = 0; i < NLAYER; ++i) {
    const float* Wi  = W_in  + (size_t)i * 2048 * 8192;
    const float* bi  = b_in  + (size_t)i * 8192;
    const float* cwi = conv_w + (size_t)i * 4096 * 4;
    const float* cbi = conv_b + (size_t)i * 4096;
    const float* Wdti= W_dt  + (size_t)i * 2 * 4096;
    const float* bdti= b_dt  + (size_t)i * 4096;
    const float* Ali = A_log + (size_t)i * 4096 * 16;
    const float* Dpi = Dp    + (size_t)i * 4096;
    const float* Woi = W_out + (size_t)i * 4096 * 2048;
    const float* boi = b_out + (size_t)i * 2048;
    const float* nwi = norm_w + (size_t)i * 2048;

    rmsnorm_kernel<<<1024, 256, 0, stream>>>(hin, nwi, ubf);
    // WT = W_in^T (8192 x 2048 bf16), per-layer (L3-hot for the GEMM)
    wtrans_kernel<<<dim3(8192 / 64, 2048 / 64), 256, 0, stream>>>(Wi, WT, 2048, 8192);
    // xz = ubf @ WT^T + b_in   (M=1024, N=8192, K=2048)
    gemm_bf16<128><<<dim3(8192 / 128, 1024 / 128), 256, 0, stream>>>(
        ubf, 2048, WT, 2048, bi, nullptr, 0, xz, 8192, 2048);
    conv_dbc_kernel<<<1024, 256, 0, stream>>>(
        xz, cwi, cbi, WxT + (size_t)i * 34 * EDIM, xab, dbc);
    // chunked scan: 3 passes
    scan_part_kernel<<<dim3(512, NCH), 256, 0, stream>>>(
        xab, dbc, Wdti, bdti, Ali, hpart, Spart);
    scan_prefix_kernel<<<(BATCH * EDIM * 16) / 256, 256, 0, stream>>>(
        hpart, Spart, Ali, seed);
    scan_final_kernel<<<dim3(512, NCH), 256, 0, stream>>>(
        xab, xz, dbc, seed, Wdti, bdti, Ali, Dpi, ybf);
    // WT = W_out^T (2048 x 4096 bf16)
    wtrans_kernel<<<dim3(2048 / 64, 4096 / 64), 256, 0, stream>>>(Woi, WT, 4096, 2048);
    // hout = hin + ybf @ WT^T + b_out   (M=1024, N=2048, K=4096)
    gemm_bf16<64><<<dim3(2048 / 64, 1024 / 128), 256, 0, stream>>>(
        ybf, 4096, WT, 4096, boi, hin, 2048, hout, 2048, 4096);
    float* tmp = hin; hin = hout; hout = tmp;
  }

  head_gemm_part<128><<<dim3(1024 / 256, BATCH, 16), 256, 0, stream>>>(
      hin + (size_t)255 * 2048, 256 * 2048, W_f, 1024, part);
  head_reduce<<<dim3(1024 / 256, BATCH), 256, 0, stream>>>(part, b_f, fb, 1024, 16, 0);
  head_gemm_part<128><<<dim3(512 / 256, BATCH, 8), 256, 0, stream>>>(
      fb, 1024, W_h1, 512, part);
  head_reduce<<<dim3(512 / 256, BATCH), 256, 0, stream>>>(part, b_h1, g1b, 512, 8, 1);
  head_gemm_part<128><<<dim3(256 / 256, BATCH, 4), 256, 0, stream>>>(
      g1b, 512, W_h2, 256, part);
  head_reduce<<<dim3(256 / 256, BATCH), 256, 0, stream>>>(part, b_h2, g2b, 256, 4, 2);
  head_final_kernel<<<1, 256, 0, stream>>>(g2b, W_h3, b_h3, out);
}

// Round 21
// 1781.069 us; speedup vs baseline: 1.0293x; 1.0293x over previous
//
#include <hip/hip_runtime.h>
#include <hip/hip_bf16.h>
#include <math.h>

#define D_MODEL 2048
#define EDIM    4096
#define NSTATE  16
#define LSEQ    256
#define BATCH   4
#define NLAYER  6
#define FDIM    80

typedef __attribute__((ext_vector_type(8))) short bf16x8;
typedef __attribute__((ext_vector_type(4))) float f32x4;

__device__ __forceinline__ float silu_f(float x) { return x / (1.f + __expf(-x)); }

__device__ __forceinline__ float softplus_f(float v) {
  return (v > 20.f) ? v : __logf(1.f + __expf(v));
}

// RNE float -> bf16 bits
__device__ __forceinline__ unsigned short f2bf(float f) {
  unsigned u = __float_as_uint(f);
  unsigned r = u + 0x7fffu + ((u >> 16) & 1u);
  return (unsigned short)(r >> 16);
}

__device__ __forceinline__ float bf2f(unsigned short u) {
  return __uint_as_float((unsigned)u << 16);
}

__device__ __forceinline__ void gload_lds16(const void* g, void* l) {
  __builtin_amdgcn_global_load_lds(
      (const __attribute__((address_space(1))) unsigned int*)g,
      (__attribute__((address_space(3))) unsigned int*)l, 16, 0, 0);
}

// ---------------- embedding ----------------
__global__ __launch_bounds__(256) void embed_kernel(
    const float* __restrict__ x, const float* __restrict__ W,
    const float* __restrict__ bias, float* __restrict__ h)
{
  int col = blockIdx.x * 256 + threadIdx.x;
  int row = blockIdx.y;
  int b = row >> 8, l = row & 255;
  const float* xp = x + (size_t)b * FDIM * LSEQ + l;
  float acc = bias[col];
  #pragma unroll 8
  for (int f = 0; f < FDIM; ++f)
    acc = fmaf(xp[(size_t)f * LSEQ], W[(size_t)f * D_MODEL + col], acc);
  h[(size_t)row * D_MODEL + col] = acc;
}

// ---------------- rmsnorm ----------------
__global__ __launch_bounds__(256) void rmsnorm_kernel(
    const float* __restrict__ h, const float* __restrict__ w, unsigned short* __restrict__ u)
{
  int row = blockIdx.x;
  const float* hr = h + (size_t)row * D_MODEL;
  float s = 0.f;
  for (int i = threadIdx.x; i < D_MODEL; i += 256) { float v = hr[i]; s = fmaf(v, v, s); }
  #pragma unroll
  for (int o = 32; o > 0; o >>= 1) s += __shfl_down(s, o);
  __shared__ float red[4];
  int lane = threadIdx.x & 63, wid = threadIdx.x >> 6;
  if (lane == 0) red[wid] = s;
  __syncthreads();
  float total = red[0] + red[1] + red[2] + red[3];
  float scale = rsqrtf(total * (1.f / D_MODEL) + 1e-5f);
  unsigned short* ur = u + (size_t)row * D_MODEL;
  for (int i = threadIdx.x; i < D_MODEL; i += 256) ur[i] = f2bf(hr[i] * scale * w[i]);
}

// ---------------- weight transpose+convert: W[K][N] f32 -> WT[N][K] bf16 ----------------
__global__ __launch_bounds__(256) void wtrans_kernel(
    const float* __restrict__ W, unsigned short* __restrict__ WT, int K, int N)
{
  __shared__ float t[64][65];
  const int k0 = blockIdx.y * 64, n0 = blockIdx.x * 64;
  const int tc = (threadIdx.x & 15) << 2;
  const int tr = threadIdx.x >> 4;
  #pragma unroll
  for (int i = 0; i < 4; ++i) {
    int r = tr + (i << 4);
    float4 v = *(const float4*)(W + (size_t)(k0 + r) * N + n0 + tc);
    t[r][tc + 0] = v.x; t[r][tc + 1] = v.y; t[r][tc + 2] = v.z; t[r][tc + 3] = v.w;
  }
  __syncthreads();
  #pragma unroll
  for (int i = 0; i < 4; ++i) {
    int rr = tr + (i << 4);
    ushort4 o;
    o.x = f2bf(t[tc + 0][rr]);
    o.y = f2bf(t[tc + 1][rr]);
    o.z = f2bf(t[tc + 2][rr]);
    o.w = f2bf(t[tc + 3][rr]);
    *(ushort4*)(WT + (size_t)(n0 + rr) * K + k0 + tc) = o;
  }
}

// ---------------- W_x transpose (all layers, once): Wx[l][e][j] -> WxT[l][j][e] ------
__global__ __launch_bounds__(256) void wxt_kernel(
    const float* __restrict__ Wx, float* __restrict__ WxT)
{
  const int e = blockIdx.x * 256 + threadIdx.x;
  const int j = blockIdx.y;
  const int l = blockIdx.z;
  WxT[((size_t)l * 34 + j) * EDIM + e] = Wx[(size_t)l * EDIM * 34 + (size_t)e * 34 + j];
}

// ---------------- bf16 MFMA GEMM (R4 structure; CT-typed output) ----------------
template<int BN, typename CT>
__global__ __launch_bounds__(256) void gemm_bf16(
    const unsigned short* __restrict__ A, int lda,
    const unsigned short* __restrict__ BT, int ldb,
    const float* bias,
    const float* resid, int ldr,
    CT* __restrict__ C, int ldc, int K)
{
  constexpr int BM = 128;
  constexpr int FN = BN / 32;
  __shared__ unsigned short As[2][BM * 32];
  __shared__ unsigned short Bs[2][BN * 32];
  const int tid  = threadIdx.x;
  const int wave = tid >> 6;
  const int lane = tid & 63;

  const int nwg = gridDim.x * gridDim.y;
  const int cpx = nwg >> 3;
  int flat = blockIdx.y * gridDim.x + blockIdx.x;
  flat = (flat & 7) * cpx + (flat >> 3);
  const int bm = (flat / gridDim.x) * BM;
  const int bn = (flat % gridDim.x) * BN;

  const int wr = (wave >> 1) * 64;
  const int wc = (wave & 1) * (BN / 2);
  const int srow = lane >> 2;
  const int scol = (lane & 3) * 8;

  auto stage = [&](int buf, int k0) {
    #pragma unroll
    for (int i = 0; i < BM / 64; ++i) {
      int c = wave + i * 4;
      gload_lds16(A + (size_t)(bm + c * 16 + srow) * lda + k0 + scol, &As[buf][c * 512]);
    }
    #pragma unroll
    for (int i = 0; i < BN / 64; ++i) {
      int c = wave + i * 4;
      gload_lds16(BT + (size_t)(bn + c * 16 + srow) * ldb + k0 + scol, &Bs[buf][c * 512]);
    }
  };

  f32x4 acc[4][FN];
  #pragma unroll
  for (int m = 0; m < 4; ++m)
    #pragma unroll
    for (int n = 0; n < FN; ++n)
      acc[m][n] = (f32x4){0.f, 0.f, 0.f, 0.f};

  stage(0, 0);
  const int nk = K >> 5;
  for (int t = 0; t < nk; ++t) {
    const int cur = t & 1;
    __syncthreads();
    if (t + 1 < nk) stage(cur ^ 1, (t + 1) << 5);
    bf16x8 af[4], bfr[FN];
    #pragma unroll
    for (int m = 0; m < 4; ++m)
      af[m] = *(const bf16x8*)&As[cur][(wr + m * 16 + (lane & 15)) * 32 + (lane >> 4) * 8];
    #pragma unroll
    for (int n = 0; n < FN; ++n)
      bfr[n] = *(const bf16x8*)&Bs[cur][(wc + n * 16 + (lane & 15)) * 32 + (lane >> 4) * 8];
    #pragma unroll
    for (int m = 0; m < 4; ++m)
      #pragma unroll
      for (int n = 0; n < FN; ++n)
        acc[m][n] = __builtin_amdgcn_mfma_f32_16x16x32_bf16(af[m], bfr[n], acc[m][n], 0, 0, 0);
  }

  const int rbase = (lane >> 4) * 4;
  const int cbase = lane & 15;
  #pragma unroll
  for (int m = 0; m < 4; ++m) {
    #pragma unroll
    for (int n = 0; n < FN; ++n) {
      const int col = bn + wc + n * 16 + cbase;
      const float bv = bias ? bias[col] : 0.f;
      #pragma unroll
      for (int r = 0; r < 4; ++r) {
        const int row = bm + wr + m * 16 + rbase + r;
        float v = acc[m][n][r] + bv;
        if (resid) v += resid[(size_t)row * ldr + col];
        if constexpr (sizeof(CT) == 2)
          C[(size_t)row * ldc + col] = f2bf(v);
        else
          C[(size_t)row * ldc + col] = v;
      }
    }
  }
}

// ---------------- fused conv+silu+dbc (xz in bf16) ----------------
__global__ __launch_bounds__(256) void conv_dbc_kernel(
    const unsigned short* __restrict__ xzb, const float* __restrict__ cw,
    const float* __restrict__ cb, const float* __restrict__ WxT,
    unsigned short* __restrict__ xab, float* __restrict__ dbc)
{
  const int row = blockIdx.x;
  const int l = row & (LSEQ - 1);
  const int tid = threadIdx.x;
  float a[16];
  const unsigned short* base_row = xzb + (size_t)row * 8192;
  #pragma unroll
  for (int k = 0; k < 16; ++k) {
    const int e = k * 256 + tid;
    float4 w = *(const float4*)(cw + (size_t)e * 4);
    const unsigned short* base = base_row + e;
    float v = cb[e];
    v = fmaf(w.w, bf2f(base[0]), v);
    if (l >= 1) v = fmaf(w.z, bf2f(base[-8192]), v);
    if (l >= 2) v = fmaf(w.y, bf2f(base[-2 * 8192]), v);
    if (l >= 3) v = fmaf(w.x, bf2f(base[-3 * 8192]), v);
    v = silu_f(v);
    a[k] = v;
    xab[(size_t)row * EDIM + e] = f2bf(v);
  }
  __shared__ float red[34][4];
  const int lane = tid & 63, wid = tid >> 6;
  #pragma unroll
  for (int j = 0; j < 34; ++j) {
    const float* wr = WxT + (size_t)j * EDIM + tid;
    float s = 0.f;
    #pragma unroll
    for (int k = 0; k < 16; ++k)
      s = fmaf(a[k], wr[k * 256], s);
    #pragma unroll
    for (int o = 32; o > 0; o >>= 1) s += __shfl_down(s, o);
    if (lane == 0) red[j][wid] = s;
  }
  __syncthreads();
  if (tid < 34)
    dbc[(size_t)row * 34 + tid] = red[tid][0] + red[tid][1] + red[tid][2] + red[tid][3];
}

// ---------------- selective scan: LDS-resident inputs (R14 structure, bf16 z) ----------
struct ScanIn { float x[4], z[4], d0[4], d1[4], B0[4], B1[4], C0[4], C1[4]; };

__device__ __forceinline__ void scan_step(
    const ScanIn& s, float& h0, float& h1,
    float w0, float w1, float bde, float Aa0, float Aa1, float dpe,
    int g, unsigned short* yp, int t0)
{
  #pragma unroll
  for (int u = 0; u < 4; ++u) {
    float v = fmaf(s.d1[u], w1, fmaf(s.d0[u], w0, bde));
    float dta = softplus_f(v);
    float dtxa = dta * s.x[u];
    h0 = fmaf(__expf(dta * Aa0), h0, dtxa * s.B0[u]);
    h1 = fmaf(__expf(dta * Aa1), h1, dtxa * s.B1[u]);
    float part = fmaf(h0, s.C0[u], h1 * s.C1[u]);
    part += __shfl_xor(part, 8);
    part += __shfl_xor(part, 16);
    part += __shfl_xor(part, 32);
    if (g == 0) {
      float yv = fmaf(dpe, s.x[u], part);
      yp[(size_t)(t0 + u) * EDIM] = f2bf(yv * silu_f(s.z[u]));
    }
  }
}

__global__ __launch_bounds__(256) void scan_kernel(
    const unsigned short* __restrict__ xab, const unsigned short* __restrict__ xzb,
    const float* __restrict__ dbc,
    const float* __restrict__ Wdt, const float* __restrict__ bdt,
    const float* __restrict__ Alog, const float* __restrict__ Dpp,
    unsigned short* __restrict__ ybf)
{
  __shared__ unsigned short sx[256 * 32];   // 16 KB
  __shared__ unsigned short sz[256 * 32];   // 16 KB
  __shared__ float          sd01[256 * 2];  //  2 KB
  __shared__ unsigned short sBC[256 * 32];  // 16 KB

  const int tid = threadIdx.x;
  const int b = blockIdx.x >> 7;
  const int chunk = blockIdx.x & 127;
  const int wave = tid >> 6;
  const int lane = tid & 63;
  const int ch = lane & 7;
  const int g = lane >> 3;
  const int we = wave * 8 + ch;
  const int e = chunk * 32 + we;

  // ---- stage working set into LDS (coalesced, once) ----
  const unsigned short* xsrc = xab + (size_t)(b << 8) * EDIM + chunk * 32;
  const unsigned short* zsrc = xzb + (size_t)(b << 8) * 8192 + EDIM + chunk * 32;
  const float* dsrc = dbc + (size_t)(b << 8) * 34;
  #pragma unroll
  for (int i = 0; i < 8; ++i) {
    int idx = i * 256 + tid;
    int t = idx >> 3, q = idx & 7;
    *(ushort4*)&sx[t * 32 + q * 4] = *(const ushort4*)&xsrc[(size_t)t * EDIM + q * 4];
    *(ushort4*)&sz[t * 32 + q * 4] = *(const ushort4*)&zsrc[(size_t)t * 8192 + q * 4];
  }
  {
    float2 v = *(const float2*)&dsrc[(size_t)tid * 34];
    *(float2*)&sd01[tid * 2] = v;
  }
  #pragma unroll
  for (int i = 0; i < 16; ++i) {
    int idx = i * 256 + tid;
    int t = idx >> 4, q = idx & 15;
    float2 v = *(const float2*)&dsrc[(size_t)t * 34 + 2 + q * 2];
    ushort2 o; o.x = f2bf(v.x); o.y = f2bf(v.y);
    *(ushort2*)&sBC[t * 32 + q * 2] = o;
  }
  __syncthreads();

  const float w0 = Wdt[e], w1 = Wdt[EDIM + e], bde = bdt[e];
  const float Aa0 = -__expf(Alog[(size_t)e * 16 + g * 2]);
  const float Aa1 = -__expf(Alog[(size_t)e * 16 + g * 2 + 1]);
  const float dpe = Dpp[e];
  float h0 = 0.f, h1 = 0.f;
  unsigned short* yp = ybf + (size_t)(b << 8) * EDIM + e;

  auto load = [&](ScanIn& s, int t0) {
    #pragma unroll
    for (int u = 0; u < 4; ++u) {
      const int t = t0 + u;
      s.x[u]  = bf2f(sx[t * 32 + we]);
      s.z[u]  = bf2f(sz[t * 32 + we]);
      s.d0[u] = sd01[t * 2];
      s.d1[u] = sd01[t * 2 + 1];
      s.B0[u] = bf2f(sBC[t * 32 + 2 * g]);
      s.B1[u] = bf2f(sBC[t * 32 + 2 * g + 1]);
      s.C0[u] = bf2f(sBC[t * 32 + 16 + 2 * g]);
      s.C1[u] = bf2f(sBC[t * 32 + 16 + 2 * g + 1]);
    }
  };

  ScanIn sa, sb;
  load(sa, 0);
  for (int t0 = 0; t0 < LSEQ; t0 += 8) {
    load(sb, t0 + 4);
    scan_step(sa, h0, h1, w0, w1, bde, Aa0, Aa1, dpe, g, yp, t0);
    if (t0 + 8 < LSEQ) load(sa, t0 + 8);
    scan_step(sb, h0, h1, w0, w1, bde, Aa0, Aa1, dpe, g, yp, t0 + 4);
  }
}

// ---------------- split-K head GEMMs ----------------
template<int KS>
__global__ __launch_bounds__(256) void head_gemm_part(
    const float* __restrict__ in, int in_stride,
    const float* __restrict__ W, int N,
    float* __restrict__ part)
{
  const int j = blockIdx.x * 256 + threadIdx.x;
  const int b = blockIdx.y;
  const int s = blockIdx.z;
  const int k0 = s * KS;
  __shared__ float sIn[KS];
  if (threadIdx.x < KS) sIn[threadIdx.x] = in[(size_t)b * in_stride + k0 + threadIdx.x];
  __syncthreads();
  float acc = 0.f;
  #pragma unroll 8
  for (int k = 0; k < KS; ++k)
    acc = fmaf(sIn[k], W[(size_t)(k0 + k) * N + j], acc);
  part[((size_t)s * gridDim.y + b) * N + j] = acc;
}

__global__ __launch_bounds__(256) void head_reduce(
    const float* __restrict__ part, const float* __restrict__ bias,
    float* __restrict__ outp, int N, int S, int act)
{
  const int j = blockIdx.x * 256 + threadIdx.x;
  const int b = blockIdx.y;
  const int B = gridDim.y;
  float acc = bias[j];
  for (int s = 0; s < S; ++s)
    acc += part[((size_t)s * B + b) * N + j];
  if (act == 1) acc = silu_f(acc);
  else if (act == 2) acc = (acc > 0.f) ? acc : 0.01f * acc;
  outp[(size_t)b * N + j] = acc;
}

__global__ __launch_bounds__(256) void head_final_kernel(
    const float* __restrict__ g2, const float* __restrict__ W,
    const float* __restrict__ bb, float* __restrict__ out)
{
  int b_idx = threadIdx.x >> 6;
  int lane = threadIdx.x & 63;
  float s = 0.f;
  #pragma unroll
  for (int i = 0; i < 4; ++i) {
    int k = lane + i * 64;
    s = fmaf(g2[b_idx * 256 + k], W[k], s);
  }
  #pragma unroll
  for (int o = 32; o > 0; o >>= 1) s += __shfl_down(s, o);
  if (lane == 0) out[b_idx] = 1.f / (1.f + __expf(-(s + bb[0])));
}

extern "C" void kernel_launch(void* const* d_in, const int* in_sizes, int n_in,
                              void* d_out, int out_size, void* d_ws, size_t ws_size,
                              hipStream_t stream)
{
  const float* x      = (const float*)d_in[0];
  const float* W_emb  = (const float*)d_in[1];
  const float* b_emb  = (const float*)d_in[2];
  const float* norm_w = (const float*)d_in[3];
  const float* W_in   = (const float*)d_in[4];
  const float* b_in   = (const float*)d_in[5];
  const float* conv_w = (const float*)d_in[6];
  const float* conv_b = (const float*)d_in[7];
  const float* W_x    = (const float*)d_in[8];
  const float* W_dt   = (const float*)d_in[9];
  const float* b_dt   = (const float*)d_in[10];
  const float* A_log  = (const float*)d_in[11];
  const float* Dp     = (const float*)d_in[12];
  const float* W_out  = (const float*)d_in[13];
  const float* b_out  = (const float*)d_in[14];
  const float* W_f    = (const float*)d_in[15];
  const float* b_f    = (const float*)d_in[16];
  const float* W_h1   = (const float*)d_in[17];
  const float* b_h1   = (const float*)d_in[18];
  const float* W_h2   = (const float*)d_in[19];
  const float* b_h2   = (const float*)d_in[20];
  const float* W_h3   = (const float*)d_in[21];
  const float* b_h3   = (const float*)d_in[22];
  float* out = (float*)d_out;

  // workspace layout
  char* ws = (char*)d_ws;
  float*          hA  = (float*)ws;                 ws += (size_t)1024 * 2048 * 4;  //  8 MB
  float*          hB  = (float*)ws;                 ws += (size_t)1024 * 2048 * 4;  //  8 MB
  unsigned short* ubf = (unsigned short*)ws;        ws += (size_t)1024 * 2048 * 2;  //  4 MB
  unsigned short* xzb = (unsigned short*)ws;        ws += (size_t)1024 * 8192 * 2;  // 16 MB
  unsigned short* xab = (unsigned short*)ws;        ws += (size_t)1024 * 4096 * 2;  //  8 MB
  float*          dbc = (float*)ws;                 ws += (size_t)1024 * 40 * 4;
  unsigned short* ybf = (unsigned short*)ws;        ws += (size_t)1024 * 4096 * 2;  //  8 MB
  unsigned short* WT  = (unsigned short*)ws;        ws += (size_t)8192 * 2048 * 2;  // 33.6 MB
  float*          WxT = (float*)ws;                 ws += (size_t)NLAYER * 34 * EDIM * 4; // 3.3 MB
  float*          part= (float*)ws;                 ws += (size_t)16 * 4 * 1024 * 4;
  float*          fb  = (float*)ws;                 ws += 4096 * 4;
  float*          g1b = (float*)ws;                 ws += 2048 * 4;
  float*          g2b = (float*)ws;                 ws += 1024 * 4;

  embed_kernel<<<dim3(D_MODEL / 256, 1024), 256, 0, stream>>>(x, W_emb, b_emb, hA);
  wxt_kernel<<<dim3(EDIM / 256, 34, NLAYER), 256, 0, stream>>>(W_x, WxT);

  float* hin = hA;
  float* hout = hB;
  for (int i = 0; i < NLAYER; ++i) {
    const float* Wi  = W_in  + (size_t)i * 2048 * 8192;
    const float* bi  = b_in  + (size_t)i * 8192;
    const float* cwi = conv_w + (size_t)i * 4096 * 4;
    const float* cbi = conv_b + (size_t)i * 4096;
    const float* Wdti= W_dt  + (size_t)i * 2 * 4096;
    const float* bdti= b_dt  + (size_t)i * 4096;
    const float* Ali = A_log + (size_t)i * 4096 * 16;
    const float* Dpi = Dp    + (size_t)i * 4096;
    const float* Woi = W_out + (size_t)i * 4096 * 2048;
    const float* boi = b_out + (size_t)i * 2048;
    const float* nwi = norm_w + (size_t)i * 2048;

    rmsnorm_kernel<<<1024, 256, 0, stream>>>(hin, nwi, ubf);
    // WT = W_in^T (8192 x 2048 bf16), per-layer (L3-hot for the GEMM)
    wtrans_kernel<<<dim3(8192 / 64, 2048 / 64), 256, 0, stream>>>(Wi, WT, 2048, 8192);
    // xzb = ubf @ WT^T + b_in   (M=1024, N=8192, K=2048) -> bf16
    gemm_bf16<128, unsigned short><<<dim3(8192 / 128, 1024 / 128), 256, 0, stream>>>(
        ubf, 2048, WT, 2048, bi, nullptr, 0, xzb, 8192, 2048);
    conv_dbc_kernel<<<1024, 256, 0, stream>>>(
        xzb, cwi, cbi, WxT + (size_t)i * 34 * EDIM, xab, dbc);
    // scan: LDS-resident inputs
    scan_kernel<<<512, 256, 0, stream>>>(xab, xzb, dbc, Wdti, bdti, Ali, Dpi, ybf);
    // WT = W_out^T (2048 x 4096 bf16)
    wtrans_kernel<<<dim3(2048 / 64, 4096 / 64), 256, 0, stream>>>(Woi, WT, 4096, 2048);
    // hout = hin + ybf @ WT^T + b_out   (M=1024, N=2048, K=4096) -> fp32
    gemm_bf16<64, float><<<dim3(2048 / 64, 1024 / 128), 256, 0, stream>>>(
        ybf, 4096, WT, 4096, boi, hin, 2048, hout, 2048, 4096);
    float* tmp = hin; hin = hout; hout = tmp;
  }

  head_gemm_part<128><<<dim3(1024 / 256, BATCH, 16), 256, 0, stream>>>(
      hin + (size_t)255 * 2048, 256 * 2048, W_f, 1024, part);
  head_reduce<<<dim3(1024 / 256, BATCH), 256, 0, stream>>>(part, b_f, fb, 1024, 16, 0);
  head_gemm_part<128><<<dim3(512 / 256, BATCH, 8), 256, 0, stream>>>(
      fb, 1024, W_h1, 512, part);
  head_reduce<<<dim3(512 / 256, BATCH), 256, 0, stream>>>(part, b_h1, g1b, 512, 8, 1);
  head_gemm_part<128><<<dim3(256 / 256, BATCH, 4), 256, 0, stream>>>(
      g1b, 512, W_h2, 256, part);
  head_reduce<<<dim3(256 / 256, BATCH), 256, 0, stream>>>(part, b_h2, g2b, 256, 4, 2);
  head_final_kernel<<<1, 256, 0, stream>>>(g2b, W_h3, b_h3, out);
}